// Round 12
// baseline (831.793 us; speedup 1.0000x reference)
//
#include <hip/hip_runtime.h>
#include <math.h>

// Capsule dynamic routing, MI355X. Round 15: ONE persistent kernel.
// R14 post-mortem: route variants bounce within noise; the timeline shows
// ~60us (1/3 of wall) is inter-dispatch gap overhead (~10us x 6 launches).
// R15: single 1024-block kernel, __launch_bounds__(256,4) (guide-sanctioned
// co-residency: k=4 -> grid <= 4*256; LDS 9.7KB, VGPR <=128 -> 4 blocks/CU
// resource-guaranteed). 5 manual grid syncs (agent-scope atomic counter,
// relaxed spin + acquire; = cooperative-groups sync in plain HIP). Counters
// zeroed by a 64B hipMemsetAsync (dispatch #1).
// Phases: A colsum->Sp ; B fold0->V ; C route1->Gp ; D fold1->V ;
//         E route2->Gp ; F fold2->squash->out.
// Route phases: NO LDS staging of u. ph1 reads u row-coalesced from global
// (8 lanes/row, 128B segments), per-64-row-half interleave with ph2 so ph2's
// u re-read is L2-hot. V from global (L2-hot). G merged via shfl_xor(32),
// stored f4-coalesced. Deterministic (atomics only on sync counters).

#define BATCH 64
#define NN    2048
#define KD    128
#define JCAP  10
#define DCAP  16
#define JDIM  160
#define EPSQ  1e-7f
#define SEGS  16      // segments per batch; 16 x 128 rows = 2048
#define SROWS 128     // rows per block-segment
#define GN    1024    // grid = 64 b x 16 seg; 4 blocks/CU x 256 CU

// ws layout: unsigned cnt[16] @float-idx 0..15 (64B, memset'd); then floats:
#define WS_SP 16                              // Sp[64][16][128]
#define WS_V  (WS_SP + BATCH * SEGS * KD)     // V[64][10][128]
#define WS_GP (WS_V + BATCH * JCAP * KD)      // Gp[64][16][10][128]

__device__ __forceinline__ void gsync(unsigned* cnt, int id) {
  __syncthreads();
  if (threadIdx.x == 0) {
    __hip_atomic_fetch_add(&cnt[id], 1u, __ATOMIC_ACQ_REL,
                           __HIP_MEMORY_SCOPE_AGENT);
    while (__hip_atomic_load(&cnt[id], __ATOMIC_RELAXED,
                             __HIP_MEMORY_SCOPE_AGENT) < GN)
      __builtin_amdgcn_s_sleep(2);
    (void)__hip_atomic_load(&cnt[id], __ATOMIC_ACQUIRE,
                            __HIP_MEMORY_SCOPE_AGENT);
  }
  __syncthreads();
}

// fold partials -> g_s[128] -> o_s[16]. mode 0: In=Sp (x0.1); mode 1: In=Gp.
__device__ __forceinline__ void fold_go(const float* __restrict__ In,
                                        const float* __restrict__ W,
                                        int b2, int j, int t, int mode,
                                        float* g_s, float* o_s) {
  if (t < KD) {
    float s = 0.f;
    if (mode == 0) {
      const float* q = In + (size_t)(b2 * SEGS) * KD + t;
#pragma unroll
      for (int sg = 0; sg < SEGS; ++sg) s += q[sg * KD];
      s *= 0.1f;
    } else {
      const float* q = In + ((size_t)(b2 * SEGS) * JCAP + j) * KD + t;
#pragma unroll
      for (int sg = 0; sg < SEGS; ++sg) s += q[(size_t)sg * JCAP * KD];
    }
    g_s[t] = s;
  }
  __syncthreads();
  if (t < DCAP) {
    float a = 0.f;
#pragma unroll 8
    for (int k = 0; k < KD; ++k) a += g_s[k] * W[k * JDIM + j * DCAP + t];
    o_s[t] = a;
  }
  __syncthreads();
}

// one routing iteration for this block's 128 rows -> Gp[b][seg][10][128]
__device__ __forceinline__ void route_phase(const float* __restrict__ ub,
                                            const float* __restrict__ vb,
                                            float* __restrict__ gb,
                                            int w, int l, float* Cs) {
  const int rx = (w << 3) + (l >> 3), kq = l & 7;   // ph1: row-slot, k-eighth
  const int j0 = (w < 2) ? 3 * w : 2 * w + 2;       // ph2 j-subsets {0,3,6,8}
  const int jn = (w < 2) ? 3 : 2;                   // {3,3,2,2}
  const int kk = l & 31, rh = l >> 5;               // ph2: k-quad, row-parity
  float4 g[3];
#pragma unroll
  for (int jj = 0; jj < 3; ++jj) g[jj] = make_float4(0.f, 0.f, 0.f, 0.f);

#pragma unroll 1
  for (int h = 0; h < 2; ++h) {                     // 64-row halves
    // ---- ph1: logits for rows ra=h*64+rx, rb=ra+32 ----
    const int ra = (h << 6) + rx, rb = ra + 32;
    float accA[JCAP], accB[JCAP];
#pragma unroll
    for (int j = 0; j < JCAP; ++j) { accA[j] = 0.f; accB[j] = 0.f; }
#pragma unroll
    for (int c = 0; c < 4; ++c) {
      const int ko = (c << 5) + (kq << 2);          // 128B-contig per 8 lanes
      const float4 ua = *(const float4*)(ub + (size_t)ra * KD + ko);
      const float4 ux = *(const float4*)(ub + (size_t)rb * KD + ko);
#pragma unroll
      for (int j = 0; j < JCAP; ++j) {
        const float4 vv = *(const float4*)(vb + (j << 7) + ko);
        accA[j] += ua.x * vv.x + ua.y * vv.y + ua.z * vv.z + ua.w * vv.w;
        accB[j] += ux.x * vv.x + ux.y * vv.y + ux.z * vv.z + ux.w * vv.w;
      }
    }
#pragma unroll
    for (int j = 0; j < JCAP; ++j) {
      accA[j] += __shfl_xor(accA[j], 1, 64);
      accA[j] += __shfl_xor(accA[j], 2, 64);
      accA[j] += __shfl_xor(accA[j], 4, 64);
      accB[j] += __shfl_xor(accB[j], 1, 64);
      accB[j] += __shfl_xor(accB[j], 2, 64);
      accB[j] += __shfl_xor(accB[j], 4, 64);
    }
    if (kq == 0) {
      float m = accA[0];
#pragma unroll
      for (int j = 1; j < JCAP; ++j) m = fmaxf(m, accA[j]);
      float ss = 0.f;
#pragma unroll
      for (int j = 0; j < JCAP; ++j) { accA[j] = __expf(accA[j] - m); ss += accA[j]; }
      float inv = 1.f / ss;
#pragma unroll
      for (int j = 0; j < JCAP; ++j) Cs[j * SROWS + ra] = accA[j] * inv;
      m = accB[0];
#pragma unroll
      for (int j = 1; j < JCAP; ++j) m = fmaxf(m, accB[j]);
      ss = 0.f;
#pragma unroll
      for (int j = 0; j < JCAP; ++j) { accB[j] = __expf(accB[j] - m); ss += accB[j]; }
      inv = 1.f / ss;
#pragma unroll
      for (int j = 0; j < JCAP; ++j) Cs[j * SROWS + rb] = accB[j] * inv;
    }
    __syncthreads();   // Cs half ready for all waves

    // ---- ph2: accumulate G over this half's 64 rows (u is L2/L1-hot) ----
#pragma unroll 8
    for (int i = 0; i < 64; i += 2) {
      const int r = (h << 6) + i + rh;
      const float4 uu = *(const float4*)(ub + (size_t)r * KD + (kk << 2));
#pragma unroll
      for (int jj = 0; jj < 3; ++jj) {
        if (jj < jn) {
          const float c = Cs[(j0 + jj) * SROWS + r];
          g[jj].x += c * uu.x; g[jj].y += c * uu.y;
          g[jj].z += c * uu.z; g[jj].w += c * uu.w;
        }
      }
    }
    // no barrier needed: next ph1 writes the OTHER Cs half (disjoint slots)
  }
  // merge row-parities and store G (f4-coalesced, 512B per wave)
#pragma unroll
  for (int jj = 0; jj < 3; ++jj) {
    if (jj < jn) {
      g[jj].x += __shfl_xor(g[jj].x, 32, 64);
      g[jj].y += __shfl_xor(g[jj].y, 32, 64);
      g[jj].z += __shfl_xor(g[jj].z, 32, 64);
      g[jj].w += __shfl_xor(g[jj].w, 32, 64);
    }
  }
  if (rh == 0) {
#pragma unroll
    for (int jj = 0; jj < 3; ++jj)
      if (jj < jn) *(float4*)&gb[(j0 + jj) * KD + (kk << 2)] = g[jj];
  }
}

__global__ __launch_bounds__(256, 4) void f_mega(const float* __restrict__ u,
                                                 const float* __restrict__ W,
                                                 float* __restrict__ out,
                                                 float* __restrict__ ws) {
  unsigned* cnt = (unsigned*)ws;
  float* Sp = ws + WS_SP;
  float* V  = ws + WS_V;
  float* Gp = ws + WS_GP;
  const int p = blockIdx.x, t = threadIdx.x;
  const int b = p >> 4, seg = p & 15;
  const int w = t >> 6, l = t & 63;
  __shared__ __align__(16) float4 red4[256];
  __shared__ float Cs[JCAP * SROWS];
  __shared__ float g_s[KD];
  __shared__ float o_s[DCAP];

  const float* ub = u + ((size_t)(b * NN + seg * SROWS)) * KD;
  const float* vb = V + (size_t)(b * JCAP) * KD;
  float* gb = Gp + ((size_t)(b * SEGS + seg)) * JCAP * KD;
  const int b2 = p / 10, jf = p - b2 * 10;          // fold-phase mapping
  const bool fold_blk = (p < BATCH * JCAP);

  // ---- A: colsum of own 128 rows -> Sp[b][seg][k] ----
  {
    const int c = t & 31, rg = t >> 5;              // 8 groups x 16 rows
    const float* pa = ub + (size_t)(rg * 16) * KD + (c << 2);
    float4 a = make_float4(0.f, 0.f, 0.f, 0.f);
#pragma unroll
    for (int r = 0; r < 16; ++r) {
      const float4 x = *(const float4*)(pa + (size_t)r * KD);
      a.x += x.x; a.y += x.y; a.z += x.z; a.w += x.w;
    }
    red4[t] = a;
    __syncthreads();
    if (t < 32) {
      float4 s4 = red4[t];
#pragma unroll
      for (int g = 1; g < 8; ++g) {
        const float4 x = red4[g * 32 + t];
        s4.x += x.x; s4.y += x.y; s4.z += x.z; s4.w += x.w;
      }
      *(float4*)&Sp[(size_t)(b * SEGS + seg) * KD + t * 4] = s4;
    }
  }
  gsync(cnt, 0);

  // ---- B: fold0 -> V0 ----
  if (fold_blk) {
    fold_go(Sp, W, b2, jf, t, 0, g_s, o_s);
    if (t < KD) {
      const float* wp = W + t * JDIM + jf * DCAP;
      float a = 0.f;
#pragma unroll
      for (int d = 0; d < DCAP; ++d) a += wp[d] * o_s[d];
      V[((size_t)(b2 * JCAP) + jf) * KD + t] = a;
    }
  }
  gsync(cnt, 1);

  // ---- C: route 1 ----
  route_phase(ub, vb, gb, w, l, Cs);
  gsync(cnt, 2);

  // ---- D: fold1 -> V1 ----
  if (fold_blk) {
    fold_go(Gp, W, b2, jf, t, 1, g_s, o_s);
    if (t < KD) {
      const float* wp = W + t * JDIM + jf * DCAP;
      float a = 0.f;
#pragma unroll
      for (int d = 0; d < DCAP; ++d) a += wp[d] * o_s[d];
      V[((size_t)(b2 * JCAP) + jf) * KD + t] = a;
    }
  }
  gsync(cnt, 3);

  // ---- E: route 2 ----
  route_phase(ub, vb, gb, w, l, Cs);
  gsync(cnt, 4);

  // ---- F: fold2 -> squash -> out ----
  if (fold_blk) {
    fold_go(Gp, W, b2, jf, t, 1, g_s, o_s);
    if (t < DCAP) {
      float s2 = 0.f;
#pragma unroll
      for (int d = 0; d < DCAP; ++d) s2 += o_s[d] * o_s[d];
      const float sc = s2 / ((1.f + s2) * sqrtf(s2 + EPSQ));
      out[(size_t)(b2 * JCAP + jf) * DCAP + t] = o_s[t] * sc;
    }
  }
}

extern "C" void kernel_launch(void* const* d_in, const int* in_sizes, int n_in,
                              void* d_out, int out_size, void* d_ws, size_t ws_size,
                              hipStream_t stream) {
  const float* u = (const float*)d_in[0];   // (64,2048,128) fp32
  const float* W = (const float*)d_in[1];   // (128,160) fp32
  float* out = (float*)d_out;               // (64,10,16) fp32
  float* ws  = (float*)d_ws;

  hipMemsetAsync(d_ws, 0, 64, stream);      // zero the 5 sync counters
  f_mega<<<GN, 256, 0, stream>>>(u, W, out, ws);
}